// Round 3
// baseline (10599.363 us; speedup 1.0000x reference)
//
#include <hip/hip_runtime.h>

#define H 512
#define NG 2048
#define BATCHN 8192
#define RTILE 32
#define STEPS 60
#define NWG (BATCHN / RTILE)  // 256

// ws layout (byte offsets)
#define WHH_OFF   0u        // 2048*512 bf16 = 2 MB, MFMA A-fragment order
#define WIHS_OFF  2097152u  // 2 MB
#define WSM_OFF   4194304u  // 32*512 bf16 = 32 KB
#define BSM_OFF   4227072u  // 32 f32

typedef short s16x8 __attribute__((ext_vector_type(8)));
typedef float f32x4 __attribute__((ext_vector_type(4)));
typedef float f32x2 __attribute__((ext_vector_type(2)));
typedef unsigned int u32x2 __attribute__((ext_vector_type(2)));

__device__ inline unsigned f2bf(float f) {
  unsigned u = __builtin_bit_cast(unsigned, f);
  return (u + 0x7fffu + ((u >> 16) & 1u)) >> 16;  // RNE, finite inputs
}
__device__ inline float bf2f(unsigned s) {
  return __builtin_bit_cast(float, s << 16);
}
__device__ inline float sigm(float x) {
  float e = __builtin_amdgcn_exp2f(-1.442695041f * x);
  return __builtin_amdgcn_rcpf(1.0f + e);
}
__device__ inline float tanh_(float x) {
  float e = __builtin_amdgcn_exp2f(2.885390082f * x);
  return 1.0f - 2.0f * __builtin_amdgcn_rcpf(1.0f + e);
}
__device__ inline f32x4 mfma16(s16x8 a, s16x8 b, f32x4 c) {
  return __builtin_amdgcn_mfma_f32_16x16x32_bf16(a, b, c, 0, 0, 0);
}
// swizzled byte address into h_lds: row b, bf16 element k
__device__ inline int haddr(int b, int k) {
  return b * 1024 + ((k * 2) ^ ((b & 7) << 4));
}

// ---------------- pack kernel: fp32 weights -> bf16 MFMA-fragment order ----
__global__ void pack_kernel(const float* __restrict__ w_ih, const float* __restrict__ w_hh,
                            const float* __restrict__ w_out, const float* __restrict__ b_out,
                            const float* __restrict__ w_mode, const float* __restrict__ b_mode,
                            unsigned char* __restrict__ ws) {
  unsigned idx = blockIdx.x * 256 + threadIdx.x;
  unsigned short* whh_p  = (unsigned short*)(ws + WHH_OFF);
  unsigned short* wihs_p = (unsigned short*)(ws + WIHS_OFF);
  unsigned short* wsm_p  = (unsigned short*)(ws + WSM_OFF);
  float* bsm = (float*)(ws + BSM_OFF);
  if (idx < 1048576u) {            // w_hh
    unsigned e = idx & 7u, lane = (idx >> 3) & 63u, kb = (idx >> 9) & 15u, nb = idx >> 13;
    unsigned n = nb * 16u + (lane & 15u), k = kb * 32u + (lane >> 4) * 8u + e;
    whh_p[idx] = (unsigned short)f2bf(w_hh[n * 512u + k]);
  } else if (idx < 2097152u) {     // w_ih social columns (2..513)
    unsigned j = idx - 1048576u;
    unsigned e = j & 7u, lane = (j >> 3) & 63u, kb = (j >> 9) & 15u, nb = j >> 13;
    unsigned n = nb * 16u + (lane & 15u), k = kb * 32u + (lane >> 4) * 8u + e;
    wihs_p[j] = (unsigned short)f2bf(w_ih[n * 514u + 2u + k]);
  } else if (idx < 2097152u + 16384u) {  // [w_out;w_mode;0] padded to 32 rows
    unsigned j = idx - 2097152u;
    unsigned e = j & 7u, lane = (j >> 3) & 63u, kb = (j >> 9) & 15u, nb = j >> 13;
    unsigned o = nb * 16u + (lane & 15u), k = kb * 32u + (lane >> 4) * 8u + e;
    float v = 0.0f;
    if (o < 12u) v = w_out[o * 512u + k];
    else if (o < 18u) v = w_mode[(o - 12u) * 512u + k];
    wsm_p[j] = (unsigned short)f2bf(v);
  } else if (idx < 2097152u + 16384u + 32u) {
    unsigned o = idx - (2097152u + 16384u);
    float v = 0.0f;
    if (o < 12u) v = b_out[o];
    else if (o < 18u) v = b_mode[o - 12u];
    bsm[o] = v;
  }
}

// ---------------- main kernel: 256 wgs x 512 thr, each wg = 32 batch rows --
__global__ __launch_bounds__(512, 2) void lstm_kernel(
    const float* __restrict__ social, const float* __restrict__ hidden,
    const float* __restrict__ cell, const float* __restrict__ w_ih,
    const float* __restrict__ b_ih, const float* __restrict__ b_hh,
    float* __restrict__ out, unsigned char* __restrict__ ws) {

  const int tid = threadIdx.x;
  const int wid = tid >> 6;    // 0..7
  const int lane = tid & 63;
  const int q = lane >> 4;     // 0..3
  const int r = lane & 15;
  const int wg = blockIdx.x;
  const int gb0 = wg * RTILE;

  // per-wave weight fragment bases (element = s16x8, 16 B)
  const s16x8* whh_w  = (const s16x8*)(ws + WHH_OFF)  + (size_t)wid * 4096 + lane;
  const s16x8* wihs_w = (const s16x8*)(ws + WIHS_OFF) + (size_t)wid * 4096 + lane;
  const s16x8* wsm_g  = (const s16x8*)(ws + WSM_OFF);
  const float* bsm    = (const float*)(ws + BSM_OFF);

  __shared__ unsigned short h_lds[RTILE * H];   // 32 KB, XOR-swizzled bf16
  __shared__ float wx_lds[NG * 2];              // 16 KB  w_ih[:, 0:2]
  __shared__ s16x8 wsm_lds[2 * 16 * 64];        // 32 KB  [w_out;w_mode] frags
  __shared__ float mode_lds[RTILE][8];
  __shared__ float x_lds[RTILE][2];

  // ---- weight register pipeline, depth 4: prologue (wihs F=0..3) ----
  s16x8 wbuf[4][4];
  #pragma unroll
  for (int d = 0; d < 4; ++d)
    #pragma unroll
    for (int g = 0; g < 4; ++g)
      wbuf[d][g] = wihs_w[g * 32768 + d * 64];

  // ---- stage social -> h_lds (bf16 swizzled), wx, wsm, zero x ----
  #pragma unroll
  for (int i = 0; i < 8; ++i) {
    int rr = i * 4 + (tid >> 7);
    int kk = (tid & 127) * 4;
    f32x4 v = *(const f32x4*)(social + (size_t)(gb0 + rr) * H + kk);
    u32x2 p;
    p[0] = f2bf(v[0]) | (f2bf(v[1]) << 16);
    p[1] = f2bf(v[2]) | (f2bf(v[3]) << 16);
    *(u32x2*)((char*)h_lds + haddr(rr, kk)) = p;
  }
  for (int n = tid; n < NG; n += 512) {
    wx_lds[n * 2 + 0] = w_ih[(size_t)n * 514 + 0];
    wx_lds[n * 2 + 1] = w_ih[(size_t)n * 514 + 1];
  }
  #pragma unroll
  for (int j = 0; j < 4; ++j) wsm_lds[j * 512 + tid] = wsm_g[j * 512 + tid];
  if (tid < RTILE * 2) ((float*)x_lds)[tid] = 0.0f;
  __syncthreads();

  // ---- S phase: S = social @ w_ihS.T + (b_ih+b_hh) -> s_reg (packed bf16) --
  u32x2 s_reg[4][4][2];
  #pragma unroll
  for (int jb = 0; jb < 4; ++jb) {
    f32x4 acc[4][2];
    #pragma unroll
    for (int g = 0; g < 4; ++g) {
      int n0 = g * 512 + wid * 64 + jb * 16 + q * 4;
      f32x4 bi = *(const f32x4*)(b_ih + n0);
      f32x4 bh = *(const f32x4*)(b_hh + n0);
      f32x4 bias = bi + bh;
      acc[g][0] = bias; acc[g][1] = bias;
    }
    #pragma unroll
    for (int kb = 0; kb < 16; ++kb) {
      const int F = jb * 16 + kb;
      const int slot = F & 3;
      s16x8 bfrag[2];
      #pragma unroll
      for (int bb = 0; bb < 2; ++bb)
        bfrag[bb] = *(const s16x8*)((char*)h_lds + haddr(bb * 16 + r, kb * 32 + q * 8));
      s16x8 af[4];
      #pragma unroll
      for (int g = 0; g < 4; ++g) af[g] = wbuf[slot][g];
      // refill slot: wihs F+4, or whh prologue for the t-loop
      if (F + 4 < 64) {
        const int jn = (F + 4) >> 4, kn = (F + 4) & 15;
        #pragma unroll
        for (int g = 0; g < 4; ++g)
          wbuf[slot][g] = wihs_w[g * 32768 + jn * 1024 + kn * 64];
      } else {
        const int Fm = F + 4 - 64;  // 0..3
        #pragma unroll
        for (int g = 0; g < 4; ++g)
          wbuf[slot][g] = whh_w[g * 32768 + Fm * 64];
      }
      #pragma unroll
      for (int g = 0; g < 4; ++g) {
        acc[g][0] = mfma16(af[g], bfrag[0], acc[g][0]);
        acc[g][1] = mfma16(af[g], bfrag[1], acc[g][1]);
      }
    }
    #pragma unroll
    for (int g = 0; g < 4; ++g) {
      #pragma unroll
      for (int bb = 0; bb < 2; ++bb) {
        s_reg[jb][g][bb][0] = f2bf(acc[g][bb][0]) | (f2bf(acc[g][bb][1]) << 16);
        s_reg[jb][g][bb][1] = f2bf(acc[g][bb][2]) | (f2bf(acc[g][bb][3]) << 16);
      }
    }
  }
  __syncthreads();

  // ---- stage h0 (overwrite social in LDS), c0 into registers ----
  #pragma unroll
  for (int i = 0; i < 8; ++i) {
    int rr = i * 4 + (tid >> 7);
    int kk = (tid & 127) * 4;
    f32x4 v = *(const f32x4*)(hidden + (size_t)(gb0 + rr) * H + kk);
    u32x2 p;
    p[0] = f2bf(v[0]) | (f2bf(v[1]) << 16);
    p[1] = f2bf(v[2]) | (f2bf(v[3]) << 16);
    *(u32x2*)((char*)h_lds + haddr(rr, kk)) = p;
  }
  float c_reg[4][2][4];
  #pragma unroll
  for (int jb = 0; jb < 4; ++jb) {
    #pragma unroll
    for (int bb = 0; bb < 2; ++bb) {
      int b = bb * 16 + r;
      int j0 = wid * 64 + jb * 16 + q * 4;
      f32x4 cv = *(const f32x4*)(cell + (size_t)(gb0 + b) * H + j0);
      #pragma unroll
      for (int e = 0; e < 4; ++e) c_reg[jb][bb][e] = cv[e];
    }
  }
  __syncthreads();

  // ---- projection constants (waves 0..3 do projection) ----
  const int nb_s = (wid >> 1) & 1;
  const int bb_s = wid & 1;
  const int b_s = bb_s * 16 + r;
  const int o0 = nb_s * 16 + q * 4;
  const bool do_c = (wid < 4);
  f32x4 bias_c = *(const f32x4*)(bsm + o0);
  const size_t MODE_BASE = (size_t)BATCHN * 720;

  for (int t = 0; t < STEPS; ++t) {
    float xv0[2], xv1[2];
    #pragma unroll
    for (int bb = 0; bb < 2; ++bb) {
      f32x2 xv = *(const f32x2*)(&x_lds[bb * 16 + r][0]);
      xv0[bb] = xv[0]; xv1[bb] = xv[1];
    }
    u32x2 hpend[4][2];
    #pragma unroll
    for (int jb = 0; jb < 4; ++jb) {
      f32x4 acc[4][2];
      // init from S (registers) + x @ w_ih[:, :2].T
      #pragma unroll
      for (int g = 0; g < 4; ++g) {
        int n0 = g * 512 + wid * 64 + jb * 16 + q * 4;
        f32x4 wxa = *(const f32x4*)(wx_lds + n0 * 2);
        f32x4 wxb = *(const f32x4*)(wx_lds + n0 * 2 + 4);
        #pragma unroll
        for (int bb = 0; bb < 2; ++bb) {
          u32x2 sv = s_reg[jb][g][bb];
          f32x4 a;
          a[0] = bf2f(sv[0] & 0xffffu); a[1] = bf2f(sv[0] >> 16);
          a[2] = bf2f(sv[1] & 0xffffu); a[3] = bf2f(sv[1] >> 16);
          a[0] += xv0[bb] * wxa[0] + xv1[bb] * wxa[1];
          a[1] += xv0[bb] * wxa[2] + xv1[bb] * wxa[3];
          a[2] += xv0[bb] * wxb[0] + xv1[bb] * wxb[1];
          a[3] += xv0[bb] * wxb[2] + xv1[bb] * wxb[3];
          acc[g][bb] = a;
        }
      }
      // h @ w_hh.T : MFMA over K=512, register weight pipeline (depth 4)
      #pragma unroll
      for (int kb = 0; kb < 16; ++kb) {
        const int F = jb * 16 + kb;
        const int slot = F & 3;
        s16x8 bfrag[2];
        #pragma unroll
        for (int bb = 0; bb < 2; ++bb)
          bfrag[bb] = *(const s16x8*)((char*)h_lds + haddr(bb * 16 + r, kb * 32 + q * 8));
        s16x8 af[4];
        #pragma unroll
        for (int g = 0; g < 4; ++g) af[g] = wbuf[slot][g];
        // refill slot with F+4 (mod 64) — wraps into next step's prologue
        {
          const int Fn = (F + 4) & 63;
          const int jn = Fn >> 4, kn = Fn & 15;
          #pragma unroll
          for (int g = 0; g < 4; ++g)
            wbuf[slot][g] = whh_w[g * 32768 + jn * 1024 + kn * 64];
        }
        #pragma unroll
        for (int g = 0; g < 4; ++g) {
          acc[g][0] = mfma16(af[g], bfrag[0], acc[g][0]);
          acc[g][1] = mfma16(af[g], bfrag[1], acc[g][1]);
        }
      }
      // LSTM cell (c in fp32 regs), h_new -> pending bf16
      #pragma unroll
      for (int bb = 0; bb < 2; ++bb) {
        unsigned hp[4];
        #pragma unroll
        for (int e = 0; e < 4; ++e) {
          float iv = sigm(acc[0][bb][e]);
          float fv = sigm(acc[1][bb][e]);
          float gv = tanh_(acc[2][bb][e]);
          float ov = sigm(acc[3][bb][e]);
          float cn = fv * c_reg[jb][bb][e] + iv * gv;
          c_reg[jb][bb][e] = cn;
          float hn = ov * tanh_(cn);
          hp[e] = f2bf(hn);
        }
        hpend[jb][bb][0] = hp[0] | (hp[1] << 16);
        hpend[jb][bb][1] = hp[2] | (hp[3] << 16);
      }
    }
    __syncthreads();  // all reads of h(t-1) done
    #pragma unroll
    for (int jb = 0; jb < 4; ++jb) {
      #pragma unroll
      for (int bb = 0; bb < 2; ++bb)
        *(u32x2*)((char*)h_lds + haddr(bb * 16 + r, wid * 64 + jb * 16 + q * 4)) = hpend[jb][bb];
    }
    __syncthreads();  // h(t) visible
    // ---- projection: [w_out; w_mode] @ h_new, two 8-deep MFMA chains ----
    if (do_c) {
      f32x4 pacc0 = bias_c;
      f32x4 pacc1 = {0.f, 0.f, 0.f, 0.f};
      #pragma unroll
      for (int kb = 0; kb < 8; ++kb) {
        s16x8 bfrag0 = *(const s16x8*)((char*)h_lds + haddr(b_s, kb * 32 + q * 8));
        s16x8 afrag0 = wsm_lds[(nb_s * 16 + kb) * 64 + lane];
        pacc0 = mfma16(afrag0, bfrag0, pacc0);
        s16x8 bfrag1 = *(const s16x8*)((char*)h_lds + haddr(b_s, (kb + 8) * 32 + q * 8));
        s16x8 afrag1 = wsm_lds[(nb_s * 16 + kb + 8) * 64 + lane];
        pacc1 = mfma16(afrag1, bfrag1, pacc1);
      }
      f32x4 pacc = pacc0 + pacc1;
      int b_glob = gb0 + b_s;
      if (o0 < 12) {
        __builtin_nontemporal_store(pacc, (f32x4*)(out + ((size_t)b_glob * 60 + t) * 12 + o0));
        if (o0 == 0) { x_lds[b_s][0] = pacc[0]; x_lds[b_s][1] = pacc[1]; }
      } else if (o0 == 12) {
        *(f32x4*)(&mode_lds[b_s][0]) = pacc;
      } else if (o0 == 16) {
        mode_lds[b_s][4] = pacc[0];
        mode_lds[b_s][5] = pacc[1];
      }
    }
    __syncthreads();  // modes + x(t) visible
    if (tid < RTILE) {
      float v0 = mode_lds[tid][0], v1 = mode_lds[tid][1], v2 = mode_lds[tid][2];
      float v3 = mode_lds[tid][3], v4 = mode_lds[tid][4], v5 = mode_lds[tid][5];
      float mx = fmaxf(fmaxf(fmaxf(v0, v1), fmaxf(v2, v3)), fmaxf(v4, v5));
      float e0 = __builtin_amdgcn_exp2f(1.442695041f * (v0 - mx));
      float e1 = __builtin_amdgcn_exp2f(1.442695041f * (v1 - mx));
      float e2 = __builtin_amdgcn_exp2f(1.442695041f * (v2 - mx));
      float e3 = __builtin_amdgcn_exp2f(1.442695041f * (v3 - mx));
      float e4 = __builtin_amdgcn_exp2f(1.442695041f * (v4 - mx));
      float e5 = __builtin_amdgcn_exp2f(1.442695041f * (v5 - mx));
      float s = e0 + e1 + e2 + e3 + e4 + e5;
      float inv = __builtin_amdgcn_rcpf(s);
      float* mo = out + MODE_BASE + (size_t)(gb0 + tid) * 360 + t * 6;
      mo[0] = e0 * inv; mo[1] = e1 * inv; mo[2] = e2 * inv;
      mo[3] = e3 * inv; mo[4] = e4 * inv; mo[5] = e5 * inv;
    }
  }
}

extern "C" void kernel_launch(void* const* d_in, const int* in_sizes, int n_in,
                              void* d_out, int out_size, void* d_ws, size_t ws_size,
                              hipStream_t stream) {
  const float* social = (const float*)d_in[0];
  const float* hidden = (const float*)d_in[1];
  const float* cell   = (const float*)d_in[2];
  const float* w_ih   = (const float*)d_in[3];
  const float* w_hh   = (const float*)d_in[4];
  const float* b_ih   = (const float*)d_in[5];
  const float* b_hh   = (const float*)d_in[6];
  const float* w_out  = (const float*)d_in[7];
  const float* b_out  = (const float*)d_in[8];
  const float* w_mode = (const float*)d_in[9];
  const float* b_mode = (const float*)d_in[10];
  unsigned char* ws = (unsigned char*)d_ws;
  float* out = (float*)d_out;

  int pack_total = 2097152 + 16384 + 32;
  hipLaunchKernelGGL(pack_kernel, dim3((pack_total + 255) / 256), dim3(256), 0, stream,
                     w_ih, w_hh, w_out, b_out, w_mode, b_mode, ws);
  hipLaunchKernelGGL(lstm_kernel, dim3(NWG), dim3(512), 0, stream,
                     social, hidden, cell, w_ih, b_ih, b_hh, out, ws);
}

// Round 4
// 4502.655 us; speedup vs baseline: 2.3540x; 2.3540x over previous
//
#include <hip/hip_runtime.h>

#define H 512
#define BATCHN 8192
#define STEPS 60

// ws byte offsets
#define WEFF_OFF   0u          // 2 MB  w_hh_eff pack (tile layout)
#define WPLAIN_OFF 2097152u    // 2 MB  w_hh pack (t=0)
#define WIHS_OFF   4194304u    // 2 MB  w_ih social cols pack (prep, old layout)
#define WSM_OFF    6291456u    // 32 KB [w_out;w_mode] pack
#define BSM_OFF    6324224u    // 128 B proj bias
#define BX1_OFF    6324352u    // 8 KB  bias_x (tile-row order)
#define BX0_OFF    6332544u    // 8 KB  zeros
#define HB0_OFF    8388608u    // 8 MB  h buffer 0 (bf16)
#define HB1_OFF    16777216u   // 8 MB  h buffer 1
#define CPACK_OFF  25165824u   // 16 MB c packed f32
#define SPACK_OFF  41943040u   // 32 MB S packed bf16

typedef short s16x8 __attribute__((ext_vector_type(8)));
typedef float f32x4 __attribute__((ext_vector_type(4)));
typedef unsigned int u32x2 __attribute__((ext_vector_type(2)));
typedef unsigned int u32x4 __attribute__((ext_vector_type(4)));

__device__ inline unsigned f2bf(float f) {
  unsigned u = __builtin_bit_cast(unsigned, f);
  return (u + 0x7fffu + ((u >> 16) & 1u)) >> 16;
}
__device__ inline float bf2f(unsigned s) {
  return __builtin_bit_cast(float, s << 16);
}
__device__ inline float sigm(float x) {
  float e = __builtin_amdgcn_exp2f(-1.442695041f * x);
  return __builtin_amdgcn_rcpf(1.0f + e);
}
__device__ inline float tanh_(float x) {
  float e = __builtin_amdgcn_exp2f(2.885390082f * x);
  return 1.0f - 2.0f * __builtin_amdgcn_rcpf(1.0f + e);
}
__device__ inline f32x4 mfma16(s16x8 a, s16x8 b, f32x4 c) {
  return __builtin_amdgcn_mfma_f32_16x16x32_bf16(a, b, c, 0, 0, 0);
}
// prep-kernel LDS swizzle (row b, bf16 elem k)
__device__ inline int haddr(int b, int k) {
  return b * 1024 + ((k * 2) ^ ((b & 7) << 4));
}

// =================== pack kernel ===================
// Tile packing for step kernel: tile T (0..127) covers hcols [4T,4T+4);
// row i in tile = (hcol&3)*4 + gate; A-frag elem: i=lane&15, k=kb*32+(lane>>4)*8+e
__global__ void pack_kernel(const float* __restrict__ w_ih, const float* __restrict__ w_hh,
                            const float* __restrict__ w_out, const float* __restrict__ b_out,
                            const float* __restrict__ w_mode, const float* __restrict__ b_mode,
                            unsigned char* __restrict__ ws) {
  unsigned idx = blockIdx.x * 256 + threadIdx.x;
  if (idx < 2097152u) {          // weff [0,1M) / wplain [1M,2M)
    unsigned j = idx & 1048575u;
    bool eff = idx < 1048576u;
    unsigned e = j & 7u, lane = (j >> 3) & 63u, kb = (j >> 9) & 15u, T = j >> 13;
    unsigned i = lane & 15u;
    unsigned hcol = T * 4u + (i >> 2), gate = i & 3u;
    unsigned n = gate * 512u + hcol;
    unsigned k = kb * 32u + (lane >> 4) * 8u + e;
    float v = w_hh[(size_t)n * 512u + k];
    if (eff) v += w_ih[(size_t)n * 514u] * w_out[k] + w_ih[(size_t)n * 514u + 1u] * w_out[512u + k];
    ((unsigned short*)(ws + (eff ? WEFF_OFF : WPLAIN_OFF)))[j] = (unsigned short)f2bf(v);
  } else if (idx < 3145728u) {   // wihs (old layout, for prep): n = nb*16+(lane&15)
    unsigned j = idx - 2097152u;
    unsigned e = j & 7u, lane = (j >> 3) & 63u, kb = (j >> 9) & 15u, nb = j >> 13;
    unsigned n = nb * 16u + (lane & 15u), k = kb * 32u + (lane >> 4) * 8u + e;
    ((unsigned short*)(ws + WIHS_OFF))[j] = (unsigned short)f2bf(w_ih[(size_t)n * 514u + 2u + k]);
  } else if (idx < 3162112u) {   // wsm: [w_out;w_mode;0] rows 0..31, natural rows
    unsigned j = idx - 3145728u;
    unsigned e = j & 7u, lane = (j >> 3) & 63u, kb = (j >> 9) & 15u, nb = j >> 13;
    unsigned o = nb * 16u + (lane & 15u), k = kb * 32u + (lane >> 4) * 8u + e;
    float v = 0.0f;
    if (o < 12u) v = w_out[o * 512u + k];
    else if (o < 18u) v = w_mode[(o - 12u) * 512u + k];
    ((unsigned short*)(ws + WSM_OFF))[j] = (unsigned short)f2bf(v);
  } else if (idx < 3162144u) {   // bsm
    unsigned o = idx - 3162112u;
    float v = 0.0f;
    if (o < 12u) v = b_out[o];
    else if (o < 18u) v = b_mode[o - 12u];
    ((float*)(ws + BSM_OFF))[o] = v;
  } else if (idx < 3164192u) {   // bias_x (tile-row order)
    unsigned m = idx - 3162144u;           // 0..2047
    unsigned T = m >> 4, i = m & 15u;
    unsigned hcol = T * 4u + (i >> 2), gate = i & 3u;
    unsigned n = gate * 512u + hcol;
    ((float*)(ws + BX1_OFF))[m] = w_ih[(size_t)n * 514u] * b_out[0] + w_ih[(size_t)n * 514u + 1u] * b_out[1];
  } else if (idx < 3166240u) {   // bx0 zeros
    ((float*)(ws + BX0_OFF))[idx - 3164192u] = 0.0f;
  }
}

// =================== prep kernel: S, h0->bf16, c0 repack ===================
__global__ __launch_bounds__(512, 2) void prep_kernel(
    const float* __restrict__ social, const float* __restrict__ hidden,
    const float* __restrict__ cell, const float* __restrict__ b_ih,
    const float* __restrict__ b_hh, unsigned char* __restrict__ ws) {
  const int tid = threadIdx.x;
  const int wid = tid >> 6;
  const int lane = tid & 63;
  const int q = lane >> 4;
  const int r = lane & 15;
  const int wg = blockIdx.x;
  const int gb0 = wg * 32;

  const s16x8* wihs_w = (const s16x8*)(ws + WIHS_OFF) + (size_t)wid * 4096 + lane;
  unsigned short* spack = (unsigned short*)(ws + SPACK_OFF);
  unsigned short* hb0 = (unsigned short*)(ws + HB0_OFF);
  float* cpackp = (float*)(ws + CPACK_OFF);

  __shared__ unsigned short h_lds[32 * H];  // 32 KB swizzled social

  // weight register pipeline depth 4
  s16x8 wbuf[4][4];
  #pragma unroll
  for (int d = 0; d < 4; ++d)
    #pragma unroll
    for (int g = 0; g < 4; ++g)
      wbuf[d][g] = wihs_w[g * 32768 + d * 64];

  // stage social -> h_lds (bf16 swizzled)
  #pragma unroll
  for (int i = 0; i < 8; ++i) {
    int rr = i * 4 + (tid >> 7);
    int kk = (tid & 127) * 4;
    f32x4 v = *(const f32x4*)(social + (size_t)(gb0 + rr) * H + kk);
    u32x2 p;
    p[0] = f2bf(v[0]) | (f2bf(v[1]) << 16);
    p[1] = f2bf(v[2]) | (f2bf(v[3]) << 16);
    *(u32x2*)((char*)h_lds + haddr(rr, kk)) = p;
  }
  __syncthreads();

  // S = social @ w_ihS.T + (b_ih+b_hh), store packed
  #pragma unroll
  for (int jb = 0; jb < 4; ++jb) {
    f32x4 acc[4][2];
    #pragma unroll
    for (int g = 0; g < 4; ++g) {
      int n0 = g * 512 + wid * 64 + jb * 16 + q * 4;
      f32x4 bi = *(const f32x4*)(b_ih + n0);
      f32x4 bh = *(const f32x4*)(b_hh + n0);
      f32x4 bias = bi + bh;
      acc[g][0] = bias; acc[g][1] = bias;
    }
    #pragma unroll
    for (int kb = 0; kb < 16; ++kb) {
      const int F = jb * 16 + kb;
      const int slot = F & 3;
      s16x8 bfrag[2];
      #pragma unroll
      for (int bb = 0; bb < 2; ++bb)
        bfrag[bb] = *(const s16x8*)((char*)h_lds + haddr(bb * 16 + r, kb * 32 + q * 8));
      s16x8 af[4];
      #pragma unroll
      for (int g = 0; g < 4; ++g) af[g] = wbuf[slot][g];
      {
        const int Fn = (F + 4) & 63;
        const int jn = Fn >> 4, kn = Fn & 15;
        #pragma unroll
        for (int g = 0; g < 4; ++g)
          wbuf[slot][g] = wihs_w[g * 32768 + jn * 1024 + kn * 64];
      }
      #pragma unroll
      for (int g = 0; g < 4; ++g) {
        acc[g][0] = mfma16(af[g], bfrag[0], acc[g][0]);
        acc[g][1] = mfma16(af[g], bfrag[1], acc[g][1]);
      }
    }
    // store S_pack: T = wid*16+jb*4+q; row m = e*4+g; 32B contiguous per lane
    #pragma unroll
    for (int bb = 0; bb < 2; ++bb) {
      unsigned wrd[8];
      #pragma unroll
      for (int j = 0; j < 8; ++j) {
        int e = j >> 1, gp = (j & 1) * 2;
        wrd[j] = f2bf(acc[gp][bb][e]) | (f2bf(acc[gp + 1][bb][e]) << 16);
      }
      int T = wid * 16 + jb * 4 + q;
      int b = gb0 + bb * 16 + r;
      char* dst = (char*)spack + ((size_t)T * 8192 + b) * 32;
      u32x4 w0; w0[0] = wrd[0]; w0[1] = wrd[1]; w0[2] = wrd[2]; w0[3] = wrd[3];
      u32x4 w1; w1[0] = wrd[4]; w1[1] = wrd[5]; w1[2] = wrd[6]; w1[3] = wrd[7];
      *(u32x4*)dst = w0;
      *(u32x4*)(dst + 16) = w1;
    }
  }

  // h0 -> bf16 natural layout
  {
    const float* hsrc = hidden + (size_t)gb0 * H;
    unsigned short* hdst = hb0 + (size_t)gb0 * H;
    int base = tid * 32;
    #pragma unroll
    for (int v8 = 0; v8 < 4; ++v8) {
      f32x4 x0 = *(const f32x4*)(hsrc + base + v8 * 8);
      f32x4 x1 = *(const f32x4*)(hsrc + base + v8 * 8 + 4);
      u32x4 pk;
      pk[0] = f2bf(x0[0]) | (f2bf(x0[1]) << 16);
      pk[1] = f2bf(x0[2]) | (f2bf(x0[3]) << 16);
      pk[2] = f2bf(x1[0]) | (f2bf(x1[1]) << 16);
      pk[3] = f2bf(x1[2]) | (f2bf(x1[3]) << 16);
      *(u32x4*)(hdst + base + v8 * 8) = pk;
    }
  }

  // c0 repack: (b,hcol) -> cpack[(((jg*32+bg)*8+w)*16+ib)*2+Tl][q*16+r]
  for (int j = 0; j < 32; ++j) {
    int flat = tid * 32 + j;
    int b = gb0 + (flat >> 9);
    int hcol = flat & 511;
    float v = cell[(size_t)b * 512 + hcol];
    int jg2 = hcol >> 6, w2 = (hcol >> 3) & 7, Tl = (hcol >> 2) & 1, q2 = hcol & 3;
    int bg2 = b >> 8, ib2 = (b >> 4) & 15, r2 = b & 15;
    int wg2 = jg2 * 32 + bg2;
    cpackp[(((size_t)(wg2 * 8 + w2) * 16 + ib2) * 2 + Tl) * 64 + q2 * 16 + r2] = v;
  }
}

// =================== per-step kernel ===================
__device__ inline void stage_load(const unsigned short* h_in, int b0, int p, int tid,
                                  s16x8 sreg[4]) {
  #pragma unroll
  for (int i = 0; i < 4; ++i) {
    int f = tid * 64 + i * 16;
    int row = f >> 10, off = f & 1023;
    sreg[i] = *(const s16x8*)((const char*)h_in + (size_t)(b0 + p * 32 + row) * 1024 + off);
  }
}
__device__ inline void stage_write(unsigned short* buf, int tid, const s16x8 sreg[4]) {
  #pragma unroll
  for (int i = 0; i < 4; ++i) {
    int f = tid * 64 + i * 16;
    int row = f >> 10, off = f & 1023;
    *(s16x8*)((char*)buf + row * 1024 + (off ^ ((row & 7) << 4))) = sreg[i];
  }
}

__global__ __launch_bounds__(512, 2) void step_kernel(
    const s16x8* __restrict__ whh, const float* __restrict__ bx,
    const unsigned short* __restrict__ spack, const s16x8* __restrict__ wsm,
    const float* __restrict__ bsm, const unsigned short* __restrict__ h_in,
    unsigned short* __restrict__ h_out, float* __restrict__ cpack,
    float* __restrict__ out, int tprev) {
  const int tid = threadIdx.x;
  const int wid = tid >> 6;
  const int lane = tid & 63;
  const int q = lane >> 4;
  const int r = lane & 15;
  const int wg = blockIdx.x;
  const int jg = wg >> 5;        // 0..7 hidden-col group (64 cols)
  const int bg = wg & 31;        // 0..31 batch group (256 rows)
  const int b0 = bg * 256;
  const size_t MODE_BASE = (size_t)BATCHN * 720;

  __shared__ s16x8 wsm_lds[2048];                 // 32 KB
  __shared__ unsigned short hinA[32 * 512];       // 32 KB swizzled
  __shared__ unsigned short hinB[32 * 512];       // 32 KB
  __shared__ unsigned short hout_lds[256 * 64];   // 32 KB swizzled
  __shared__ float mode_lds[8][16][8];            // 4 KB

  // register-resident A fragments (2 tiles x 16 kb = 128 VGPR)
  s16x8 A0[16], A1[16];
  #pragma unroll
  for (int kb = 0; kb < 16; ++kb) {
    A0[kb] = whh[(size_t)((jg * 16 + wid * 2 + 0) * 16 + kb) * 64 + lane];
    A1[kb] = whh[(size_t)((jg * 16 + wid * 2 + 1) * 16 + kb) * 64 + lane];
  }
  // c registers
  float creg[16][2];
  #pragma unroll
  for (int ib = 0; ib < 16; ++ib) {
    creg[ib][0] = cpack[(size_t)(((wg * 8 + wid) * 16 + ib) * 2 + 0) * 64 + lane];
    creg[ib][1] = cpack[(size_t)(((wg * 8 + wid) * 16 + ib) * 2 + 1) * 64 + lane];
  }
  f32x4 bxv0 = *(const f32x4*)(bx + (jg * 16 + wid * 2 + 0) * 16 + q * 4);
  f32x4 bxv1 = *(const f32x4*)(bx + (jg * 16 + wid * 2 + 1) * 16 + q * 4);
  f32x4 pb0 = *(const f32x4*)(bsm + q * 4);
  f32x4 pb1 = *(const f32x4*)(bsm + 16 + q * 4);
  #pragma unroll
  for (int i = 0; i < 4; ++i) wsm_lds[i * 512 + tid] = wsm[i * 512 + tid];

  s16x8 sreg[4];
  stage_load(h_in, b0, 0, tid, sreg);
  stage_write(hinA, tid, sreg);
  stage_load(h_in, b0, 1, tid, sreg);
  __syncthreads();

  #pragma unroll
  for (int rr = 0; rr < 8; ++rr) {
    if (rr < 7) {
      unsigned short* wb = ((rr + 1) & 1) ? hinB : hinA;
      stage_write(wb, tid, sreg);
      if (rr < 6) stage_load(h_in, b0, rr + 2, tid, sreg);
    }
    const unsigned short* hbuf = (rr & 1) ? hinB : hinA;
    const bool dop = (wid == rr) && (tprev >= 0);
    #pragma unroll
    for (int ib2 = 0; ib2 < 2; ++ib2) {
      const int bt = rr * 2 + ib2;
      const int b = b0 + bt * 16 + r;
      u32x2 sv0 = *(const u32x2*)((const char*)spack +
                    ((size_t)(jg * 16 + wid * 2 + 0) * 8192 + b) * 32 + q * 8);
      u32x2 sv1 = *(const u32x2*)((const char*)spack +
                    ((size_t)(jg * 16 + wid * 2 + 1) * 8192 + b) * 32 + q * 8);
      f32x4 acc0, acc1;
      acc0[0] = bf2f(sv0[0] & 0xffffu) + bxv0[0];
      acc0[1] = bf2f(sv0[0] >> 16)     + bxv0[1];
      acc0[2] = bf2f(sv0[1] & 0xffffu) + bxv0[2];
      acc0[3] = bf2f(sv0[1] >> 16)     + bxv0[3];
      acc1[0] = bf2f(sv1[0] & 0xffffu) + bxv1[0];
      acc1[1] = bf2f(sv1[0] >> 16)     + bxv1[1];
      acc1[2] = bf2f(sv1[1] & 0xffffu) + bxv1[2];
      acc1[3] = bf2f(sv1[1] >> 16)     + bxv1[3];
      #pragma unroll
      for (int kb = 0; kb < 16; ++kb) {
        s16x8 bfrag = *(const s16x8*)((const char*)hbuf + (ib2 * 16 + r) * 1024 +
                        ((kb * 64 + q * 16) ^ ((r & 7) << 4)));
        acc0 = mfma16(A0[kb], bfrag, acc0);
        acc1 = mfma16(A1[kb], bfrag, acc1);
      }
      // cell update + h write to LDS
      #pragma unroll
      for (int Tl = 0; Tl < 2; ++Tl) {
        f32x4 ac = Tl ? acc1 : acc0;
        float iv = sigm(ac[0]), fv = sigm(ac[1]), gv = tanh_(ac[2]), ov = sigm(ac[3]);
        float cn = fv * creg[bt][Tl] + iv * gv;
        creg[bt][Tl] = cn;
        float hn = ov * tanh_(cn);
        int col = wid * 8 + Tl * 4 + q;
        int row = bt * 16 + r;
        *(unsigned short*)((char*)hout_lds + row * 128 + ((col * 2) ^ ((r & 7) << 4))) =
            (unsigned short)f2bf(hn);
      }
      // projection of h(t_prev+1)=h_in for this bt (one wave per round)
      if (dop) {
        f32x4 p0 = pb0, p1 = pb1;
        #pragma unroll
        for (int kb = 0; kb < 16; ++kb) {
          s16x8 bfrag = *(const s16x8*)((const char*)hbuf + (ib2 * 16 + r) * 1024 +
                          ((kb * 64 + q * 16) ^ ((r & 7) << 4)));
          p0 = mfma16(wsm_lds[kb * 64 + lane], bfrag, p0);
          p1 = mfma16(wsm_lds[(16 + kb) * 64 + lane], bfrag, p1);
        }
        if (q < 3) *(f32x4*)(out + ((size_t)b * 60 + tprev) * 12 + q * 4) = p0;
        if (q == 3) *(f32x4*)(&mode_lds[wid][r][0]) = p0;
        if (q == 0) { mode_lds[wid][r][4] = p1[0]; mode_lds[wid][r][5] = p1[1]; }
        if (q == 1) {
          float v0 = mode_lds[wid][r][0], v1 = mode_lds[wid][r][1], v2 = mode_lds[wid][r][2];
          float v3 = mode_lds[wid][r][3], v4 = mode_lds[wid][r][4], v5 = mode_lds[wid][r][5];
          float mx = fmaxf(fmaxf(fmaxf(v0, v1), fmaxf(v2, v3)), fmaxf(v4, v5));
          float e0 = __builtin_amdgcn_exp2f(1.442695041f * (v0 - mx));
          float e1 = __builtin_amdgcn_exp2f(1.442695041f * (v1 - mx));
          float e2 = __builtin_amdgcn_exp2f(1.442695041f * (v2 - mx));
          float e3 = __builtin_amdgcn_exp2f(1.442695041f * (v3 - mx));
          float e4 = __builtin_amdgcn_exp2f(1.442695041f * (v4 - mx));
          float e5 = __builtin_amdgcn_exp2f(1.442695041f * (v5 - mx));
          float s = e0 + e1 + e2 + e3 + e4 + e5;
          float inv = __builtin_amdgcn_rcpf(s);
          float* mo = out + MODE_BASE + (size_t)b * 360 + tprev * 6;
          mo[0] = e0 * inv; mo[1] = e1 * inv; mo[2] = e2 * inv;
          mo[3] = e3 * inv; mo[4] = e4 * inv; mo[5] = e5 * inv;
        }
      }
    }
    __syncthreads();
  }

  // flush h_out (256 rows x 64 cols bf16), de-swizzle
  #pragma unroll
  for (int i = 0; i < 4; ++i) {
    int f = tid * 64 + i * 16;
    int row = f >> 7, off = f & 127;
    s16x8 v = *(const s16x8*)((const char*)hout_lds + row * 128 + (off ^ ((row & 7) << 4)));
    *(s16x8*)((char*)h_out + (size_t)(b0 + row) * 1024 + jg * 128 + off) = v;
  }
  // c writeback
  #pragma unroll
  for (int ib = 0; ib < 16; ++ib) {
    cpack[(size_t)(((wg * 8 + wid) * 16 + ib) * 2 + 0) * 64 + lane] = creg[ib][0];
    cpack[(size_t)(((wg * 8 + wid) * 16 + ib) * 2 + 1) * 64 + lane] = creg[ib][1];
  }
}

// =================== final projection (pred/modes for t=59) ===================
__global__ __launch_bounds__(256) void projf_kernel(
    const unsigned short* __restrict__ h_in, const s16x8* __restrict__ wsm,
    const float* __restrict__ bsm, float* __restrict__ out) {
  const int tid = threadIdx.x;
  const int wid = tid >> 6;   // 0..3
  const int lane = tid & 63;
  const int q = lane >> 4;
  const int r = lane & 15;
  const int wg = blockIdx.x;
  const int b0 = wg * 32;
  const int bt = wid & 1, T = wid >> 1;
  const size_t MODE_BASE = (size_t)BATCHN * 720;
  __shared__ float mbuf[32][8];

  f32x4 pacc = *(const f32x4*)(bsm + T * 16 + q * 4);
  #pragma unroll
  for (int kb = 0; kb < 16; ++kb) {
    s16x8 bfrag = *(const s16x8*)((const char*)h_in +
                    (size_t)(b0 + bt * 16 + r) * 1024 + kb * 64 + q * 16);
    s16x8 af = wsm[(T * 16 + kb) * 64 + lane];
    pacc = mfma16(af, bfrag, pacc);
  }
  int b = b0 + bt * 16 + r;
  if (T == 0) {
    if (q < 3) *(f32x4*)(out + ((size_t)b * 60 + 59) * 12 + q * 4) = pacc;
    if (q == 3) *(f32x4*)(&mbuf[bt * 16 + r][0]) = pacc;
  } else {
    if (q == 0) { mbuf[bt * 16 + r][4] = pacc[0]; mbuf[bt * 16 + r][5] = pacc[1]; }
  }
  __syncthreads();
  if (tid < 32) {
    float v0 = mbuf[tid][0], v1 = mbuf[tid][1], v2 = mbuf[tid][2];
    float v3 = mbuf[tid][3], v4 = mbuf[tid][4], v5 = mbuf[tid][5];
    float mx = fmaxf(fmaxf(fmaxf(v0, v1), fmaxf(v2, v3)), fmaxf(v4, v5));
    float e0 = __builtin_amdgcn_exp2f(1.442695041f * (v0 - mx));
    float e1 = __builtin_amdgcn_exp2f(1.442695041f * (v1 - mx));
    float e2 = __builtin_amdgcn_exp2f(1.442695041f * (v2 - mx));
    float e3 = __builtin_amdgcn_exp2f(1.442695041f * (v3 - mx));
    float e4 = __builtin_amdgcn_exp2f(1.442695041f * (v4 - mx));
    float e5 = __builtin_amdgcn_exp2f(1.442695041f * (v5 - mx));
    float s = e0 + e1 + e2 + e3 + e4 + e5;
    float inv = __builtin_amdgcn_rcpf(s);
    float* mo = out + MODE_BASE + (size_t)(b0 + tid) * 360 + 59 * 6;
    mo[0] = e0 * inv; mo[1] = e1 * inv; mo[2] = e2 * inv;
    mo[3] = e3 * inv; mo[4] = e4 * inv; mo[5] = e5 * inv;
  }
}

extern "C" void kernel_launch(void* const* d_in, const int* in_sizes, int n_in,
                              void* d_out, int out_size, void* d_ws, size_t ws_size,
                              hipStream_t stream) {
  const float* social = (const float*)d_in[0];
  const float* hidden = (const float*)d_in[1];
  const float* cell   = (const float*)d_in[2];
  const float* w_ih   = (const float*)d_in[3];
  const float* w_hh   = (const float*)d_in[4];
  const float* b_ih   = (const float*)d_in[5];
  const float* b_hh   = (const float*)d_in[6];
  const float* w_out  = (const float*)d_in[7];
  const float* b_out  = (const float*)d_in[8];
  const float* w_mode = (const float*)d_in[9];
  const float* b_mode = (const float*)d_in[10];
  unsigned char* ws = (unsigned char*)d_ws;
  float* out = (float*)d_out;

  hipLaunchKernelGGL(pack_kernel, dim3((3166240u + 255u) / 256u), dim3(256), 0, stream,
                     w_ih, w_hh, w_out, b_out, w_mode, b_mode, ws);
  hipLaunchKernelGGL(prep_kernel, dim3(256), dim3(512), 0, stream,
                     social, hidden, cell, b_ih, b_hh, ws);

  const s16x8* weff   = (const s16x8*)(ws + WEFF_OFF);
  const s16x8* wplain = (const s16x8*)(ws + WPLAIN_OFF);
  const s16x8* wsm    = (const s16x8*)(ws + WSM_OFF);
  const float* bsm    = (const float*)(ws + BSM_OFF);
  const float* bx1    = (const float*)(ws + BX1_OFF);
  const float* bx0    = (const float*)(ws + BX0_OFF);
  const unsigned short* spack = (const unsigned short*)(ws + SPACK_OFF);
  unsigned short* hb[2] = {(unsigned short*)(ws + HB0_OFF), (unsigned short*)(ws + HB1_OFF)};
  float* cpack = (float*)(ws + CPACK_OFF);

  for (int s = 0; s < STEPS; ++s) {
    hipLaunchKernelGGL(step_kernel, dim3(256), dim3(512), 0, stream,
                       (s == 0) ? wplain : weff, (s == 0) ? bx0 : bx1,
                       spack, wsm, bsm, hb[s & 1], hb[(s + 1) & 1], cpack, out, s - 1);
  }
  hipLaunchKernelGGL(projf_kernel, dim3(256), dim3(256), 0, stream,
                     hb[0], wsm, bsm, out);
}